// Round 7
// baseline (999.951 us; speedup 1.0000x reference)
//
#include <hip/hip_runtime.h>
#include <cstddef>

#define EPSBN 1e-5f

typedef __attribute__((ext_vector_type(8))) short bf16x8;
typedef __attribute__((ext_vector_type(4))) float f32x4;

__device__ __forceinline__ float gelu_f(float x) {
    return 0.5f * x * (1.0f + erff(x * 0.70710678118654752440f));
}

__device__ __forceinline__ float bfu2f(unsigned short u) {
    unsigned v = ((unsigned)u) << 16;
    return __uint_as_float(v);
}

__device__ __forceinline__ unsigned short f2bfu(float f) {
    unsigned u = __float_as_uint(f);
    unsigned r = (u + 0x7fffu + ((u >> 16) & 1u)) >> 16;  // RNE
    return (unsigned short)r;
}

// XOR swizzle valid only where it is a bijection of the row: first 256 bytes.
__device__ __forceinline__ int swz_byte(int byte, int r) {
    return (byte < 256) ? (byte ^ ((r & 7) << 4)) : byte;
}

__device__ __forceinline__ void voxel_idx(const float* __restrict__ pts, int i,
                                          int& vx, int& vy, int& vz) {
    float x = pts[i * 3 + 0], y = pts[i * 3 + 1], z = pts[i * 3 + 2];
    vx = (int)floorf(x / 0.1f);
    vy = (int)floorf(y / 0.1f);
    vz = (int)floorf(z / 0.1f);
}

__device__ __forceinline__ unsigned flip_hash(const float* __restrict__ pts, int i) {
    int vx, vy, vz;
    voxel_idx(pts, i, vx, vy, vz);
    unsigned h = (unsigned)vx * 73856093u + (unsigned)vy * 19349663u + (unsigned)vz * 83492791u;
    return h ^ 0x80000000u;  // unsigned order == signed int32 order
}

__global__ void fill_f32(float* p, float v, int n) {
    int i = blockIdx.x * blockDim.x + threadIdx.x;
    if (i < n) p[i] = v;
}

__global__ void key_kernel(const float* __restrict__ pts, int* __restrict__ key,
                           int* __restrict__ cnt, int P) {
    int i = blockIdx.x * blockDim.x + threadIdx.x;
    if (i >= P) return;
    unsigned fk = flip_hash(pts, i);
    key[i] = (int)fk;
    atomicAdd(&cnt[fk >> 16], 1);
}

// ---- hierarchical exclusive scan of 65536 ints: scanA (256 blocks) -> scanB (1 block) -> scanC ----
__global__ void scanA(const int* __restrict__ in, int* __restrict__ out, int* __restrict__ bsum) {
    __shared__ int s[256];
    int tid = threadIdx.x;
    int i = blockIdx.x * 256 + tid;
    int v = in[i];
    s[tid] = v;
    __syncthreads();
    for (int off = 1; off < 256; off <<= 1) {
        int t = (tid >= off) ? s[tid - off] : 0;
        __syncthreads();
        s[tid] += t;
        __syncthreads();
    }
    out[i] = s[tid] - v;  // exclusive
    if (tid == 255) bsum[blockIdx.x] = s[255];
}

__global__ void scanB(int* bsum) {
    __shared__ int s[256];
    int tid = threadIdx.x;
    int v = bsum[tid];
    s[tid] = v;
    __syncthreads();
    for (int off = 1; off < 256; off <<= 1) {
        int t = (tid >= off) ? s[tid - off] : 0;
        __syncthreads();
        s[tid] += t;
        __syncthreads();
    }
    bsum[tid] = s[tid] - v;  // exclusive
}

__global__ void scanC(int* __restrict__ out, const int* __restrict__ bsum) {
    out[blockIdx.x * 256 + threadIdx.x] += bsum[blockIdx.x];
}

__global__ void scatter_kernel(const int* __restrict__ key, const int* __restrict__ off,
                               int* __restrict__ fill, int* __restrict__ lo, int P) {
    int i = blockIdx.x * blockDim.x + threadIdx.x;
    if (i >= P) return;
    unsigned fk = (unsigned)key[i];
    int hi = fk >> 16;
    int pos = off[hi] + atomicAdd(&fill[hi], 1);
    lo[pos] = (int)(fk & 0xFFFFu);
}

// per-bucket in-place selection sort + dedupe (no scratch arrays; mean n~4)
__global__ void bucket_unique(const int* __restrict__ off, const int* __restrict__ cnt,
                              int* __restrict__ lo, int* __restrict__ dcnt, int NB) {
    int b = blockIdx.x * blockDim.x + threadIdx.x;
    if (b >= NB) return;
    int n = cnt[b];
    int base = off[b];
    if (n == 0) { dcnt[b] = 0; return; }
    for (int j = 0; j < n - 1; ++j) {
        int mi = j, mv = lo[base + j];
        for (int k = j + 1; k < n; ++k) {
            int v = lo[base + k];
            if (v < mv) { mv = v; mi = k; }
        }
        if (mi != j) { lo[base + mi] = lo[base + j]; lo[base + j] = mv; }
    }
    int d = 0, prev = -1;
    for (int j = 0; j < n; ++j) {
        int v = lo[base + j];
        if (j == 0 || v != prev) lo[base + d++] = v;
        prev = v;
    }
    dcnt[b] = d;
}

__global__ void rank_kernel(const int* __restrict__ key, const int* __restrict__ off,
                            const int* __restrict__ dcnt, const int* __restrict__ lo,
                            const int* __restrict__ dpre, int* __restrict__ inv, int P) {
    int i = blockIdx.x * blockDim.x + threadIdx.x;
    if (i >= P) return;
    unsigned fk = (unsigned)key[i];
    int hi = fk >> 16;
    int l = (int)(fk & 0xFFFFu);
    int base = off[hi];
    int d = dcnt[hi];
    int r = 0;
    for (int j = 0; j < d; ++j) {
        if (lo[base + j] == l) { r = j; break; }
    }
    inv[i] = dpre[hi] + r;
}

__global__ void accum_kernel(const float* __restrict__ pts, const int* __restrict__ inv,
                             float* __restrict__ counts, float* __restrict__ csum,
                             int* __restrict__ winner, int P) {
    int i = blockIdx.x * blockDim.x + threadIdx.x;
    if (i >= P) return;
    int s = inv[i];
    atomicAdd(&counts[s], 1.0f);
    atomicAdd(&csum[s * 3 + 0], pts[i * 3 + 0]);
    atomicAdd(&csum[s * 3 + 1], pts[i * 3 + 1]);
    atomicAdd(&csum[s * 3 + 2], pts[i * 3 + 2]);
    atomicMax(&winner[s], i);  // last point wins (XLA scatter order)
}

__global__ void centroid_kernel(float* __restrict__ csum, const float* __restrict__ counts, int P) {
    int s = blockIdx.x * blockDim.x + threadIdx.x;
    if (s >= P) return;
    float d = fmaxf(counts[s], 1.0f);
    csum[s * 3 + 0] /= d;
    csum[s * 3 + 1] /= d;
    csum[s * 3 + 2] /= d;
}

__global__ void uvox_kernel(const float* __restrict__ pts, const int* __restrict__ inv,
                            const int* __restrict__ winner, float* __restrict__ out2,
                            int P, int N) {
    int i = blockIdx.x * blockDim.x + threadIdx.x;
    if (i >= P) return;
    int s = inv[i];
    if (winner[s] != i) return;
    int vx, vy, vz;
    voxel_idx(pts, i, vx, vy, vz);
    out2[0 * (size_t)P + s] = (float)(i / N);
    out2[1 * (size_t)P + s] = (float)vx;
    out2[2 * (size_t)P + s] = (float)vy;
    out2[3 * (size_t)P + s] = (float)vz;
}

__global__ void norm_kernel(const float* __restrict__ pts, const int* __restrict__ inv,
                            const float* __restrict__ cent, float* __restrict__ out3, int P) {
    int i = blockIdx.x * blockDim.x + threadIdx.x;
    if (i >= P) return;
    int s = inv[i];
    out3[i * 3 + 0] = pts[i * 3 + 0] - cent[s * 3 + 0];
    out3[i * 3 + 1] = pts[i * 3 + 1] - cent[s * 3 + 1];
    out3[i * 3 + 2] = pts[i * 3 + 2] - cent[s * 3 + 2];
}

// layer-1 stats only (raw1 recomputed in layer-2 staging). 128 threads = cols, 64 rows/block.
__global__ void l1stats(const float* __restrict__ norm, const float* __restrict__ w1g,
                        float* __restrict__ spart, int P) {
    int c = threadIdx.x;
    int row0 = blockIdx.x * 64;
    float w0 = w1g[c], wa = w1g[128 + c], wb = w1g[256 + c];
    float s = 0.f, q = 0.f;
    for (int r = 0; r < 64; ++r) {
        const float* nr = norm + (size_t)(row0 + r) * 3;
        float v = nr[0] * w0 + nr[1] * wa + nr[2] * wb;
        s += v;
        q += v * v;
    }
    int b = blockIdx.x & 63;
    atomicAdd(&spart[b * 256 + c], s);
    atomicAdd(&spart[b * 256 + 128 + c], q);
}

__global__ void finalize_bn(const float* __restrict__ spart, const float* __restrict__ g,
                            const float* __restrict__ b, float* __restrict__ prm, int P) {
    int c = threadIdx.x;  // 128
    float s = 0.f, q = 0.f;
    for (int t = 0; t < 64; ++t) {
        s += spart[t * 256 + c];
        q += spart[t * 256 + 128 + c];
    }
    float m = s / (float)P;
    float var = fmaxf(q / (float)P - m * m, 0.f);
    float A = g[c] * rsqrtf(var + EPSBN);
    prm[c] = A;
    prm[128 + c] = b[c] - A * m;
}

// pre-transpose weights to bf16 W^T[n][k]; layer-3 K reordered [act(128), pts(3), cent(3), 0-pad]
__global__ void prep_wt(const float* __restrict__ w2, const float* __restrict__ w3,
                        const float* __restrict__ w4, unsigned short* __restrict__ wt2,
                        unsigned short* __restrict__ wt3, unsigned short* __restrict__ wt4) {
    int t = blockIdx.x * 256 + threadIdx.x;  // 53248 tasks
    if (t < 16384) {
        int n = t >> 7, k = t & 127;
        wt2[n * 128 + k] = f2bfu(w2[k * 128 + n]);
    } else if (t < 16384 + 20480) {
        int u = t - 16384;
        int n = u / 160, k = u - n * 160;
        float v = 0.f;
        if (k < 134) {
            int r = (k < 128) ? (k + 3) : ((k < 131) ? (k - 128) : k);
            v = w3[r * 128 + n];
        }
        wt3[n * 160 + k] = f2bfu(v);
    } else if (t < 53248) {
        int u = t - 36864;
        int n = u >> 7, k = u & 127;
        wt4[n * 128 + k] = f2bfu(w4[k * 128 + n]);
    }
}

// MFMA GEMM layer, 512 threads (8 waves, 2x4 wave grid), 128x128 tile.
// MODE 0: A = BNGELU(act_raw bf16; prm)
// MODE 1: A = BNGELU(norm @ w1; prm)        (layer 2; act_raw unused -> norm, w1g used)
// MODE 2: A = [BNGELU(act_raw), pts, cent, 0-pad]  (layer 3, KPAD=160)
template <int KPAD, int MODE>
__launch_bounds__(512, 4)
__global__ void gemm_layer(const unsigned short* __restrict__ act_raw,
                           const float* __restrict__ norm,
                           const float* __restrict__ w1g,
                           const float* __restrict__ prm,
                           const float* __restrict__ pts,
                           const float* __restrict__ cent,
                           const unsigned short* __restrict__ wt,
                           unsigned short* __restrict__ out_raw,
                           float* __restrict__ spart, int P) {
    __shared__ __align__(16) unsigned short sA[128 * KPAD];
    __shared__ __align__(16) unsigned short sW[128 * KPAD];
    const int tid = threadIdx.x;
    const int row0 = blockIdx.x * 128;

    // ---- stage A cols 0..127 (16B/thread/iter) ----
    for (int e = tid * 8; e < 128 * 128; e += 4096) {
        int r = e >> 7, k = e & 127;
        unsigned short vs[8];
        if constexpr (MODE == 1) {
            const float* nr = norm + (size_t)(row0 + r) * 3;
            float n0 = nr[0], n1 = nr[1], n2 = nr[2];
#pragma unroll
            for (int kk = 0; kk < 8; ++kk) {
                int kc = k + kk;
                float raw = n0 * w1g[kc] + n1 * w1g[128 + kc] + n2 * w1g[256 + kc];
                vs[kk] = f2bfu(gelu_f(prm[kc] * raw + prm[128 + kc]));
            }
        } else {
            uint4 rv = *(const uint4*)&act_raw[(size_t)(row0 + r) * 128 + k];
            const unsigned short* rs = (const unsigned short*)&rv;
#pragma unroll
            for (int kk = 0; kk < 8; ++kk) {
                int kc = k + kk;
                vs[kk] = f2bfu(gelu_f(prm[kc] * bfu2f(rs[kk]) + prm[128 + kc]));
            }
        }
        uint4 pk;
        unsigned* pw = (unsigned*)&pk;
#pragma unroll
        for (int w = 0; w < 4; ++w)
            pw[w] = (unsigned)vs[2 * w] | ((unsigned)vs[2 * w + 1] << 16);
        *(uint4*)((char*)sA + r * (KPAD * 2) + swz_byte(k * 2, r)) = pk;
    }
    if constexpr (MODE == 2) {
        // cols 128..159: pts, cent, zeros (byte>=256: unswizzled)
        for (int t = tid; t < 128 * 8; t += 512) {
            int r = t >> 3, ch = t & 7;
            float a = 0.f, b = 0.f, c = 0.f, d = 0.f;
            if (ch == 0) {
                a = pts[(size_t)(row0 + r) * 3 + 0];
                b = pts[(size_t)(row0 + r) * 3 + 1];
                c = pts[(size_t)(row0 + r) * 3 + 2];
                d = cent[(size_t)(row0 + r) * 3 + 0];
            } else if (ch == 1) {
                a = cent[(size_t)(row0 + r) * 3 + 1];
                b = cent[(size_t)(row0 + r) * 3 + 2];
            }
            unsigned lo = (unsigned)f2bfu(a) | ((unsigned)f2bfu(b) << 16);
            unsigned hi = (unsigned)f2bfu(c) | ((unsigned)f2bfu(d) << 16);
            int byte = swz_byte((128 + ch * 4) * 2, r);
            *(uint2*)((char*)sA + r * (KPAD * 2) + byte) = make_uint2(lo, hi);
        }
    }
    // ---- stage W^T ----
    for (int e = tid * 8; e < 128 * KPAD; e += 4096) {
        int r = e / KPAD, k = e - r * KPAD;
        uint4 w = *(const uint4*)&wt[e];
        *(uint4*)((char*)sW + r * (KPAD * 2) + swz_byte(k * 2, r)) = w;
    }
    __syncthreads();

    const int lane = tid & 63;
    const int wid = tid >> 6;           // 0..7
    const int wm = wid >> 2, wn = wid & 3;  // 2x4 wave grid: 64x32 per wave
    const int lrow = lane & 15;
    const int kg = lane >> 4;

    f32x4 acc[4][2] = {};
#pragma unroll
    for (int ks = 0; ks < KPAD / 32; ++ks) {
        bf16x8 a[4], b[2];
        int kbyte = ks * 64 + kg * 16;
#pragma unroll
        for (int i = 0; i < 4; ++i) {
            int r = wm * 64 + i * 16 + lrow;
            a[i] = *(const bf16x8*)((const char*)sA + r * (KPAD * 2) + swz_byte(kbyte, r));
        }
#pragma unroll
        for (int j = 0; j < 2; ++j) {
            int n = wn * 32 + j * 16 + lrow;
            b[j] = *(const bf16x8*)((const char*)sW + n * (KPAD * 2) + swz_byte(kbyte, n));
        }
#pragma unroll
        for (int i = 0; i < 4; ++i)
#pragma unroll
            for (int j = 0; j < 2; ++j)
                acc[i][j] = __builtin_amdgcn_mfma_f32_16x16x32_bf16(a[i], b[j], acc[i][j], 0, 0, 0);
    }

    // ---- C write (bf16) + column stats ----
    float s[2] = {0.f, 0.f}, q[2] = {0.f, 0.f};
#pragma unroll
    for (int i = 0; i < 4; ++i) {
        int rbase = row0 + wm * 64 + i * 16 + kg * 4;
#pragma unroll
        for (int j = 0; j < 2; ++j) {
            int col = wn * 32 + j * 16 + lrow;
#pragma unroll
            for (int reg = 0; reg < 4; ++reg) {
                float v = acc[i][j][reg];
                out_raw[(size_t)(rbase + reg) * 128 + col] = f2bfu(v);
                s[j] += v;
                q[j] += v * v;
            }
        }
    }

    __syncthreads();  // all MFMA LDS reads done; reuse sA as reduction buffer
    float* red = (float*)sA;
    if (tid < 256) red[tid] = 0.f;
    __syncthreads();
#pragma unroll
    for (int j = 0; j < 2; ++j) {
        int col = wn * 32 + j * 16 + lrow;
        atomicAdd(&red[col], s[j]);
        atomicAdd(&red[128 + col], q[j]);
    }
    __syncthreads();
    if (tid < 256) atomicAdd(&spart[(blockIdx.x & 63) * 256 + tid], red[tid]);
}

__global__ void bn_gelu_out(const unsigned short* __restrict__ raw, const float* __restrict__ prm,
                            float* __restrict__ out, int n) {
    int i = blockIdx.x * blockDim.x + threadIdx.x;
    int idx4 = i * 4;
    if (idx4 >= n) return;
    ushort4 v = *(const ushort4*)&raw[idx4];
    int c = idx4 & 127;
    float4 o;
    o.x = gelu_f(prm[c + 0] * bfu2f(v.x) + prm[128 + c + 0]);
    o.y = gelu_f(prm[c + 1] * bfu2f(v.y) + prm[128 + c + 1]);
    o.z = gelu_f(prm[c + 2] * bfu2f(v.z) + prm[128 + c + 2]);
    o.w = gelu_f(prm[c + 3] * bfu2f(v.w) + prm[128 + c + 3]);
    *(float4*)&out[idx4] = o;
}

extern "C" void kernel_launch(void* const* d_in, const int* in_sizes, int n_in,
                              void* d_out, int out_size, void* d_ws, size_t ws_size,
                              hipStream_t stream) {
    const float* pts = (const float*)d_in[0];
    const float* w1 = (const float*)d_in[1];
    const float* g1 = (const float*)d_in[2];
    const float* b1 = (const float*)d_in[3];
    const float* w2 = (const float*)d_in[4];
    const float* g2 = (const float*)d_in[5];
    const float* b2 = (const float*)d_in[6];
    const float* w3 = (const float*)d_in[7];
    const float* g3 = (const float*)d_in[8];
    const float* b3 = (const float*)d_in[9];
    const float* w4 = (const float*)d_in[10];
    const float* g4 = (const float*)d_in[11];
    const float* b4 = (const float*)d_in[12];

    const int P = in_sizes[0] / 3;  // 262144
    const int N = P / 4;            // B=4
    const int NB = 65536;

    float* out0 = (float*)d_out;               // aggregated (P,128)
    float* out2 = out0 + (size_t)P * 128;      // uvox.T (4,P)
    float* out3 = out2 + (size_t)P * 4;        // norm_points (P,3)

    char* ws = (char*)d_ws;
    size_t P4 = (size_t)P * 4;
    int* d_key = (int*)(ws + 0 * P4);
    int* d_lo = (int*)(ws + 1 * P4);
    int* d_inv = (int*)(ws + 2 * P4);
    float* d_counts = (float*)(ws + 3 * P4);
    float* d_csum = (float*)(ws + 4 * P4);   // 3P floats; becomes centroids
    int* d_winner = (int*)(ws + 7 * P4);
    char* base8 = ws + 8 * P4;
    int* d_cnt = (int*)(base8);
    int* d_off = (int*)(base8 + 1 * 262144);
    int* d_fill = (int*)(base8 + 2 * 262144);
    int* d_dcnt = (int*)(base8 + 3 * 262144);
    int* d_dpre = (int*)(base8 + 4 * 262144);
    float* d_stats = (float*)(base8 + 5 * 262144);            // 4*64*256 f32 = 256KB
    float* d_params = (float*)(base8 + 6 * 262144);           // 4*256 f32
    int* d_bsum = (int*)(base8 + 6 * 262144 + 16384);         // 256 ints
    unsigned short* d_wt2 = (unsigned short*)(base8 + 6 * 262144 + 65536);
    unsigned short* d_wt3 = d_wt2 + 128 * 128;
    unsigned short* d_wt4 = d_wt3 + 128 * 160;
    char* bufbase = base8 + 6 * 262144 + 65536 + 262144;
    unsigned short* d_bufA = (unsigned short*)bufbase;                         // (P,128) bf16
    unsigned short* d_bufB = (unsigned short*)(bufbase + (size_t)P * 128 * 2); // (P,128) bf16

    const int nb = (P + 255) / 256;

    (void)hipMemsetAsync(d_cnt, 0, 262144, stream);
    (void)hipMemsetAsync(d_fill, 0, 262144, stream);
    (void)hipMemsetAsync(d_counts, 0, P4, stream);
    (void)hipMemsetAsync(d_csum, 0, 3 * P4, stream);
    (void)hipMemsetAsync(d_winner, 0xFF, P4, stream);
    (void)hipMemsetAsync(d_stats, 0, 262144, stream);
    fill_f32<<<(4 * P + 255) / 256, 256, 0, stream>>>(out2, -1.0f, 4 * P);

    // ---- unique-rank pipeline ----
    key_kernel<<<nb, 256, 0, stream>>>(pts, d_key, d_cnt, P);
    scanA<<<256, 256, 0, stream>>>(d_cnt, d_off, d_bsum);
    scanB<<<1, 256, 0, stream>>>(d_bsum);
    scanC<<<256, 256, 0, stream>>>(d_off, d_bsum);
    scatter_kernel<<<nb, 256, 0, stream>>>(d_key, d_off, d_fill, d_lo, P);
    bucket_unique<<<NB / 256, 256, 0, stream>>>(d_off, d_cnt, d_lo, d_dcnt, NB);
    scanA<<<256, 256, 0, stream>>>(d_dcnt, d_dpre, d_bsum);
    scanB<<<1, 256, 0, stream>>>(d_bsum);
    scanC<<<256, 256, 0, stream>>>(d_dpre, d_bsum);
    rank_kernel<<<nb, 256, 0, stream>>>(d_key, d_off, d_dcnt, d_lo, d_dpre, d_inv, P);

    // ---- voxel pooling ----
    accum_kernel<<<nb, 256, 0, stream>>>(pts, d_inv, d_counts, d_csum, d_winner, P);
    centroid_kernel<<<nb, 256, 0, stream>>>(d_csum, d_counts, P);
    uvox_kernel<<<nb, 256, 0, stream>>>(pts, d_inv, d_winner, out2, P, N);
    norm_kernel<<<nb, 256, 0, stream>>>(pts, d_inv, d_csum, out3, P);

    // ---- weights -> bf16 W^T ----
    prep_wt<<<208, 256, 0, stream>>>(w2, w3, w4, d_wt2, d_wt3, d_wt4);

    // ---- layer 1: stats only ----
    l1stats<<<P / 64, 128, 0, stream>>>(out3, w1, d_stats, P);
    finalize_bn<<<1, 128, 0, stream>>>(d_stats, g1, b1, d_params, P);

    // ---- layer 2 (recompute norm@w1 in staging) -> pos_raw (bufA) ----
    gemm_layer<128, 1><<<P / 128, 512, 0, stream>>>(
        nullptr, out3, w1, d_params, nullptr, nullptr, d_wt2, d_bufA, d_stats + 1 * 64 * 256, P);
    finalize_bn<<<1, 128, 0, stream>>>(d_stats + 1 * 64 * 256, g2, b2, d_params + 256, P);

    // ---- layer 3 (concat) -> af_raw (bufB) ----
    gemm_layer<160, 2><<<P / 128, 512, 0, stream>>>(
        d_bufA, nullptr, nullptr, d_params + 256, pts, d_csum, d_wt3, d_bufB, d_stats + 2 * 64 * 256, P);
    finalize_bn<<<1, 128, 0, stream>>>(d_stats + 2 * 64 * 256, g3, b3, d_params + 512, P);

    // ---- layer 4 -> agg_raw (bufA) ----
    gemm_layer<128, 0><<<P / 128, 512, 0, stream>>>(
        d_bufB, nullptr, nullptr, d_params + 512, nullptr, nullptr, d_wt4, d_bufA, d_stats + 3 * 64 * 256, P);
    finalize_bn<<<1, 128, 0, stream>>>(d_stats + 3 * 64 * 256, g4, b4, d_params + 768, P);

    // ---- final BN+GELU -> f32 out ----
    bn_gelu_out<<<(P * 128 / 4 + 255) / 256, 256, 0, stream>>>(
        d_bufA, d_params + 768, out0, P * 128);
}

// Round 8
// 677.753 us; speedup vs baseline: 1.4754x; 1.4754x over previous
//
#include <hip/hip_runtime.h>
#include <cstddef>

#define EPSBN 1e-5f

typedef __attribute__((ext_vector_type(8))) short bf16x8;
typedef __attribute__((ext_vector_type(4))) float f32x4;

__device__ __forceinline__ float gelu_f(float x) {
    return 0.5f * x * (1.0f + erff(x * 0.70710678118654752440f));
}

__device__ __forceinline__ float bfu2f(unsigned short u) {
    unsigned v = ((unsigned)u) << 16;
    return __uint_as_float(v);
}

__device__ __forceinline__ unsigned short f2bfu(float f) {
    unsigned u = __float_as_uint(f);
    unsigned r = (u + 0x7fffu + ((u >> 16) & 1u)) >> 16;  // RNE
    return (unsigned short)r;
}

// XOR swizzle valid only where it is a bijection of the row: first 256 bytes.
__device__ __forceinline__ int swz_byte(int byte, int r) {
    return (byte < 256) ? (byte ^ ((r & 7) << 4)) : byte;
}

__device__ __forceinline__ void voxel_idx(const float* __restrict__ pts, int i,
                                          int& vx, int& vy, int& vz) {
    float x = pts[i * 3 + 0], y = pts[i * 3 + 1], z = pts[i * 3 + 2];
    vx = (int)floorf(x / 0.1f);
    vy = (int)floorf(y / 0.1f);
    vz = (int)floorf(z / 0.1f);
}

__device__ __forceinline__ unsigned flip_hash(const float* __restrict__ pts, int i) {
    int vx, vy, vz;
    voxel_idx(pts, i, vx, vy, vz);
    unsigned h = (unsigned)vx * 73856093u + (unsigned)vy * 19349663u + (unsigned)vz * 83492791u;
    return h ^ 0x80000000u;  // unsigned order == signed int32 order
}

__global__ void fill_f32(float* p, float v, int n) {
    int i = blockIdx.x * blockDim.x + threadIdx.x;
    if (i < n) p[i] = v;
}

__global__ void key_kernel(const float* __restrict__ pts, int* __restrict__ key,
                           int* __restrict__ cnt, int P) {
    int i = blockIdx.x * blockDim.x + threadIdx.x;
    if (i >= P) return;
    unsigned fk = flip_hash(pts, i);
    key[i] = (int)fk;
    atomicAdd(&cnt[fk >> 16], 1);
}

// ---- hierarchical exclusive scan of 65536 ints ----
__global__ void scanA(const int* __restrict__ in, int* __restrict__ out, int* __restrict__ bsum) {
    __shared__ int s[256];
    int tid = threadIdx.x;
    int i = blockIdx.x * 256 + tid;
    int v = in[i];
    s[tid] = v;
    __syncthreads();
    for (int off = 1; off < 256; off <<= 1) {
        int t = (tid >= off) ? s[tid - off] : 0;
        __syncthreads();
        s[tid] += t;
        __syncthreads();
    }
    out[i] = s[tid] - v;  // exclusive
    if (tid == 255) bsum[blockIdx.x] = s[255];
}

__global__ void scanB(int* bsum) {
    __shared__ int s[256];
    int tid = threadIdx.x;
    int v = bsum[tid];
    s[tid] = v;
    __syncthreads();
    for (int off = 1; off < 256; off <<= 1) {
        int t = (tid >= off) ? s[tid - off] : 0;
        __syncthreads();
        s[tid] += t;
        __syncthreads();
    }
    bsum[tid] = s[tid] - v;  // exclusive
}

__global__ void scanC(int* __restrict__ out, const int* __restrict__ bsum) {
    out[blockIdx.x * 256 + threadIdx.x] += bsum[blockIdx.x];
}

__global__ void scatter_kernel(const int* __restrict__ key, const int* __restrict__ off,
                               int* __restrict__ fill, int* __restrict__ lo, int P) {
    int i = blockIdx.x * blockDim.x + threadIdx.x;
    if (i >= P) return;
    unsigned fk = (unsigned)key[i];
    int hi = fk >> 16;
    int pos = off[hi] + atomicAdd(&fill[hi], 1);
    lo[pos] = (int)(fk & 0xFFFFu);
}

// per-bucket in-place selection sort + dedupe (no scratch arrays; mean n~4)
__global__ void bucket_unique(const int* __restrict__ off, const int* __restrict__ cnt,
                              int* __restrict__ lo, int* __restrict__ dcnt, int NB) {
    int b = blockIdx.x * blockDim.x + threadIdx.x;
    if (b >= NB) return;
    int n = cnt[b];
    int base = off[b];
    if (n == 0) { dcnt[b] = 0; return; }
    for (int j = 0; j < n - 1; ++j) {
        int mi = j, mv = lo[base + j];
        for (int k = j + 1; k < n; ++k) {
            int v = lo[base + k];
            if (v < mv) { mv = v; mi = k; }
        }
        if (mi != j) { lo[base + mi] = lo[base + j]; lo[base + j] = mv; }
    }
    int d = 0, prev = -1;
    for (int j = 0; j < n; ++j) {
        int v = lo[base + j];
        if (j == 0 || v != prev) lo[base + d++] = v;
        prev = v;
    }
    dcnt[b] = d;
}

__global__ void rank_kernel(const int* __restrict__ key, const int* __restrict__ off,
                            const int* __restrict__ dcnt, const int* __restrict__ lo,
                            const int* __restrict__ dpre, int* __restrict__ inv, int P) {
    int i = blockIdx.x * blockDim.x + threadIdx.x;
    if (i >= P) return;
    unsigned fk = (unsigned)key[i];
    int hi = fk >> 16;
    int l = (int)(fk & 0xFFFFu);
    int base = off[hi];
    int d = dcnt[hi];
    int r = 0;
    for (int j = 0; j < d; ++j) {
        if (lo[base + j] == l) { r = j; break; }
    }
    inv[i] = dpre[hi] + r;
}

__global__ void accum_kernel(const float* __restrict__ pts, const int* __restrict__ inv,
                             float* __restrict__ counts, float* __restrict__ csum,
                             int* __restrict__ winner, int P) {
    int i = blockIdx.x * blockDim.x + threadIdx.x;
    if (i >= P) return;
    int s = inv[i];
    atomicAdd(&counts[s], 1.0f);
    atomicAdd(&csum[s * 3 + 0], pts[i * 3 + 0]);
    atomicAdd(&csum[s * 3 + 1], pts[i * 3 + 1]);
    atomicAdd(&csum[s * 3 + 2], pts[i * 3 + 2]);
    atomicMax(&winner[s], i);  // last point wins (XLA scatter order)
}

__global__ void centroid_kernel(float* __restrict__ csum, const float* __restrict__ counts, int P) {
    int s = blockIdx.x * blockDim.x + threadIdx.x;
    if (s >= P) return;
    float d = fmaxf(counts[s], 1.0f);
    csum[s * 3 + 0] /= d;
    csum[s * 3 + 1] /= d;
    csum[s * 3 + 2] /= d;
}

__global__ void uvox_kernel(const float* __restrict__ pts, const int* __restrict__ inv,
                            const int* __restrict__ winner, float* __restrict__ out2,
                            int P, int N) {
    int i = blockIdx.x * blockDim.x + threadIdx.x;
    if (i >= P) return;
    int s = inv[i];
    if (winner[s] != i) return;
    int vx, vy, vz;
    voxel_idx(pts, i, vx, vy, vz);
    out2[0 * (size_t)P + s] = (float)(i / N);
    out2[1 * (size_t)P + s] = (float)vx;
    out2[2 * (size_t)P + s] = (float)vy;
    out2[3 * (size_t)P + s] = (float)vz;
}

__global__ void norm_kernel(const float* __restrict__ pts, const int* __restrict__ inv,
                            const float* __restrict__ cent, float* __restrict__ out3, int P) {
    int i = blockIdx.x * blockDim.x + threadIdx.x;
    if (i >= P) return;
    int s = inv[i];
    out3[i * 3 + 0] = pts[i * 3 + 0] - cent[s * 3 + 0];
    out3[i * 3 + 1] = pts[i * 3 + 1] - cent[s * 3 + 1];
    out3[i * 3 + 2] = pts[i * 3 + 2] - cent[s * 3 + 2];
}

// layer-1 stats only (raw1 recomputed in layer-2 staging). 128 threads = cols, 64 rows/block.
__global__ void l1stats(const float* __restrict__ norm, const float* __restrict__ w1g,
                        float* __restrict__ spart, int P) {
    int c = threadIdx.x;
    int row0 = blockIdx.x * 64;
    float w0 = w1g[c], wa = w1g[128 + c], wb = w1g[256 + c];
    float s = 0.f, q = 0.f;
    for (int r = 0; r < 64; ++r) {
        const float* nr = norm + (size_t)(row0 + r) * 3;
        float v = nr[0] * w0 + nr[1] * wa + nr[2] * wb;
        s += v;
        q += v * v;
    }
    int b = blockIdx.x & 63;
    atomicAdd(&spart[b * 256 + c], s);
    atomicAdd(&spart[b * 256 + 128 + c], q);
}

__global__ void finalize_bn(const float* __restrict__ spart, const float* __restrict__ g,
                            const float* __restrict__ b, float* __restrict__ prm, int P) {
    int c = threadIdx.x;  // 128
    float s = 0.f, q = 0.f;
    for (int t = 0; t < 64; ++t) {
        s += spart[t * 256 + c];
        q += spart[t * 256 + 128 + c];
    }
    float m = s / (float)P;
    float var = fmaxf(q / (float)P - m * m, 0.f);
    float A = g[c] * rsqrtf(var + EPSBN);
    prm[c] = A;
    prm[128 + c] = b[c] - A * m;
}

// pre-transpose weights to bf16 W^T[n][k]; layer-3 K reordered [act(128), pts(3), cent(3), 0-pad]
__global__ void prep_wt(const float* __restrict__ w2, const float* __restrict__ w3,
                        const float* __restrict__ w4, unsigned short* __restrict__ wt2,
                        unsigned short* __restrict__ wt3, unsigned short* __restrict__ wt4) {
    int t = blockIdx.x * 256 + threadIdx.x;  // 53248 tasks
    if (t < 16384) {
        int n = t >> 7, k = t & 127;
        wt2[n * 128 + k] = f2bfu(w2[k * 128 + n]);
    } else if (t < 16384 + 20480) {
        int u = t - 16384;
        int n = u / 160, k = u - n * 160;
        float v = 0.f;
        if (k < 134) {
            int r = (k < 128) ? (k + 3) : ((k < 131) ? (k - 128) : k);
            v = w3[r * 128 + n];
        }
        wt3[n * 160 + k] = f2bfu(v);
    } else if (t < 53248) {
        int u = t - 36864;
        int n = u >> 7, k = u & 127;
        wt4[n * 128 + k] = f2bfu(w4[k * 128 + n]);
    }
}

// MFMA GEMM layer, 256 threads (4 waves, 2x2 wave grid), 128x128 tile.
// Proven Round-4 shape (VGPR 88, 102us @ KPAD=160); MODE added for staging source.
// MODE 0: A = BNGELU(act_raw bf16; prm)
// MODE 1: A = BNGELU(norm @ w1; prm)
// MODE 2: A = [BNGELU(act_raw), pts, cent, 0-pad]  (KPAD=160)
template <int KPAD, int MODE>
__launch_bounds__(256, 2)
__global__ void gemm_layer(const unsigned short* __restrict__ act_raw,
                           const float* __restrict__ norm,
                           const float* __restrict__ w1g,
                           const float* __restrict__ prm,
                           const float* __restrict__ pts,
                           const float* __restrict__ cent,
                           const unsigned short* __restrict__ wt,
                           unsigned short* __restrict__ out_raw,
                           float* __restrict__ spart, int P) {
    __shared__ __align__(16) unsigned short sA[128 * KPAD];
    __shared__ __align__(16) unsigned short sW[128 * KPAD];
    const int tid = threadIdx.x;
    const int row0 = blockIdx.x * 128;

    // ---- stage A cols 0..127 (4 bf16 = 8B per thread-iter) ----
    for (int e = tid * 4; e < 128 * 128; e += 1024) {
        int r = e >> 7, k = e & 127;
        float v0, v1, v2, v3;
        if constexpr (MODE == 1) {
            const float* nr = norm + (size_t)(row0 + r) * 3;
            float n0 = nr[0], n1 = nr[1], n2 = nr[2];
            float r0 = n0 * w1g[k + 0] + n1 * w1g[128 + k + 0] + n2 * w1g[256 + k + 0];
            float r1 = n0 * w1g[k + 1] + n1 * w1g[128 + k + 1] + n2 * w1g[256 + k + 1];
            float r2 = n0 * w1g[k + 2] + n1 * w1g[128 + k + 2] + n2 * w1g[256 + k + 2];
            float r3 = n0 * w1g[k + 3] + n1 * w1g[128 + k + 3] + n2 * w1g[256 + k + 3];
            float4 pA = *(const float4*)&prm[k];
            float4 pB = *(const float4*)&prm[128 + k];
            v0 = gelu_f(pA.x * r0 + pB.x);
            v1 = gelu_f(pA.y * r1 + pB.y);
            v2 = gelu_f(pA.z * r2 + pB.z);
            v3 = gelu_f(pA.w * r3 + pB.w);
        } else {
            ushort4 rv = *(const ushort4*)&act_raw[(size_t)(row0 + r) * 128 + k];
            float4 pA = *(const float4*)&prm[k];
            float4 pB = *(const float4*)&prm[128 + k];
            v0 = gelu_f(pA.x * bfu2f(rv.x) + pB.x);
            v1 = gelu_f(pA.y * bfu2f(rv.y) + pB.y);
            v2 = gelu_f(pA.z * bfu2f(rv.z) + pB.z);
            v3 = gelu_f(pA.w * bfu2f(rv.w) + pB.w);
        }
        unsigned lo = (unsigned)f2bfu(v0) | ((unsigned)f2bfu(v1) << 16);
        unsigned hi = (unsigned)f2bfu(v2) | ((unsigned)f2bfu(v3) << 16);
        *(uint2*)((char*)sA + r * (KPAD * 2) + swz_byte(k * 2, r)) = make_uint2(lo, hi);
    }
    if constexpr (MODE == 2) {
        // cols 128..159: pts, cent, zeros
        const int NCH = (KPAD - 128) / 4;
        for (int t = tid; t < 128 * NCH; t += 256) {
            int r = t / NCH, ch = t - r * NCH;
            float a = 0.f, b = 0.f, c = 0.f, d = 0.f;
            if (ch == 0) {
                a = pts[(size_t)(row0 + r) * 3 + 0];
                b = pts[(size_t)(row0 + r) * 3 + 1];
                c = pts[(size_t)(row0 + r) * 3 + 2];
                d = cent[(size_t)(row0 + r) * 3 + 0];
            } else if (ch == 1) {
                a = cent[(size_t)(row0 + r) * 3 + 1];
                b = cent[(size_t)(row0 + r) * 3 + 2];
            }
            unsigned lo = (unsigned)f2bfu(a) | ((unsigned)f2bfu(b) << 16);
            unsigned hi = (unsigned)f2bfu(c) | ((unsigned)f2bfu(d) << 16);
            int byte = swz_byte((128 + ch * 4) * 2, r);
            *(uint2*)((char*)sA + r * (KPAD * 2) + byte) = make_uint2(lo, hi);
        }
    }
    // ---- stage W^T (8B/thread-iter) ----
    for (int e = tid * 4; e < 128 * KPAD; e += 1024) {
        int r = e / KPAD, k = e - r * KPAD;
        uint2 w = *(const uint2*)&wt[e];
        *(uint2*)((char*)sW + r * (KPAD * 2) + swz_byte(k * 2, r)) = w;
    }
    __syncthreads();

    const int lane = tid & 63;
    const int wid = tid >> 6;
    const int wm = wid >> 1, wn = wid & 1;  // 2x2 wave grid, 64x64 each
    const int lrow = lane & 15;
    const int kg = lane >> 4;

    f32x4 acc[4][4] = {};
#pragma unroll
    for (int ks = 0; ks < KPAD / 32; ++ks) {
        bf16x8 a[4], b[4];
        int kbyte = ks * 64 + kg * 16;
#pragma unroll
        for (int i = 0; i < 4; ++i) {
            int r = wm * 64 + i * 16 + lrow;
            a[i] = *(const bf16x8*)((const char*)sA + r * (KPAD * 2) + swz_byte(kbyte, r));
        }
#pragma unroll
        for (int j = 0; j < 4; ++j) {
            int n = wn * 64 + j * 16 + lrow;
            b[j] = *(const bf16x8*)((const char*)sW + n * (KPAD * 2) + swz_byte(kbyte, n));
        }
#pragma unroll
        for (int i = 0; i < 4; ++i)
#pragma unroll
            for (int j = 0; j < 4; ++j)
                acc[i][j] = __builtin_amdgcn_mfma_f32_16x16x32_bf16(a[i], b[j], acc[i][j], 0, 0, 0);
    }

    // ---- C write (bf16) + column stats ----
    float s[4] = {0.f, 0.f, 0.f, 0.f}, q[4] = {0.f, 0.f, 0.f, 0.f};
#pragma unroll
    for (int i = 0; i < 4; ++i) {
        int rbase = row0 + wm * 64 + i * 16 + kg * 4;
#pragma unroll
        for (int j = 0; j < 4; ++j) {
            int col = wn * 64 + j * 16 + lrow;
#pragma unroll
            for (int reg = 0; reg < 4; ++reg) {
                float v = acc[i][j][reg];
                out_raw[(size_t)(rbase + reg) * 128 + col] = f2bfu(v);
                s[j] += v;
                q[j] += v * v;
            }
        }
    }

    __syncthreads();  // all MFMA LDS reads done; reuse sA as reduction buffer
    float* red = (float*)sA;
    red[tid] = 0.f;
    __syncthreads();
#pragma unroll
    for (int j = 0; j < 4; ++j) {
        int col = wn * 64 + j * 16 + lrow;
        atomicAdd(&red[col], s[j]);
        atomicAdd(&red[128 + col], q[j]);
    }
    __syncthreads();
    atomicAdd(&spart[(blockIdx.x & 63) * 256 + tid], red[tid]);
}

__global__ void bn_gelu_out(const unsigned short* __restrict__ raw, const float* __restrict__ prm,
                            float* __restrict__ out, int n) {
    int i = blockIdx.x * blockDim.x + threadIdx.x;
    int idx4 = i * 4;
    if (idx4 >= n) return;
    ushort4 v = *(const ushort4*)&raw[idx4];
    int c = idx4 & 127;
    float4 o;
    o.x = gelu_f(prm[c + 0] * bfu2f(v.x) + prm[128 + c + 0]);
    o.y = gelu_f(prm[c + 1] * bfu2f(v.y) + prm[128 + c + 1]);
    o.z = gelu_f(prm[c + 2] * bfu2f(v.z) + prm[128 + c + 2]);
    o.w = gelu_f(prm[c + 3] * bfu2f(v.w) + prm[128 + c + 3]);
    *(float4*)&out[idx4] = o;
}

extern "C" void kernel_launch(void* const* d_in, const int* in_sizes, int n_in,
                              void* d_out, int out_size, void* d_ws, size_t ws_size,
                              hipStream_t stream) {
    const float* pts = (const float*)d_in[0];
    const float* w1 = (const float*)d_in[1];
    const float* g1 = (const float*)d_in[2];
    const float* b1 = (const float*)d_in[3];
    const float* w2 = (const float*)d_in[4];
    const float* g2 = (const float*)d_in[5];
    const float* b2 = (const float*)d_in[6];
    const float* w3 = (const float*)d_in[7];
    const float* g3 = (const float*)d_in[8];
    const float* b3 = (const float*)d_in[9];
    const float* w4 = (const float*)d_in[10];
    const float* g4 = (const float*)d_in[11];
    const float* b4 = (const float*)d_in[12];

    const int P = in_sizes[0] / 3;  // 262144
    const int N = P / 4;            // B=4
    const int NB = 65536;

    float* out0 = (float*)d_out;               // aggregated (P,128)
    float* out2 = out0 + (size_t)P * 128;      // uvox.T (4,P)
    float* out3 = out2 + (size_t)P * 4;        // norm_points (P,3)

    char* ws = (char*)d_ws;
    size_t P4 = (size_t)P * 4;
    int* d_key = (int*)(ws + 0 * P4);
    int* d_lo = (int*)(ws + 1 * P4);
    int* d_inv = (int*)(ws + 2 * P4);
    float* d_counts = (float*)(ws + 3 * P4);
    float* d_csum = (float*)(ws + 4 * P4);   // 3P floats; becomes centroids
    int* d_winner = (int*)(ws + 7 * P4);
    char* base8 = ws + 8 * P4;
    int* d_cnt = (int*)(base8);
    int* d_off = (int*)(base8 + 1 * 262144);
    int* d_fill = (int*)(base8 + 2 * 262144);
    int* d_dcnt = (int*)(base8 + 3 * 262144);
    int* d_dpre = (int*)(base8 + 4 * 262144);
    float* d_stats = (float*)(base8 + 5 * 262144);            // 4*64*256 f32 = 256KB
    float* d_params = (float*)(base8 + 6 * 262144);           // 4*256 f32
    int* d_bsum = (int*)(base8 + 6 * 262144 + 16384);         // 256 ints
    unsigned short* d_wt2 = (unsigned short*)(base8 + 6 * 262144 + 65536);
    unsigned short* d_wt3 = d_wt2 + 128 * 128;
    unsigned short* d_wt4 = d_wt3 + 128 * 160;
    char* bufbase = base8 + 6 * 262144 + 65536 + 262144;
    unsigned short* d_bufA = (unsigned short*)bufbase;                         // (P,128) bf16
    unsigned short* d_bufB = (unsigned short*)(bufbase + (size_t)P * 128 * 2); // (P,128) bf16

    const int nb = (P + 255) / 256;

    (void)hipMemsetAsync(d_cnt, 0, 262144, stream);
    (void)hipMemsetAsync(d_fill, 0, 262144, stream);
    (void)hipMemsetAsync(d_counts, 0, P4, stream);
    (void)hipMemsetAsync(d_csum, 0, 3 * P4, stream);
    (void)hipMemsetAsync(d_winner, 0xFF, P4, stream);
    (void)hipMemsetAsync(d_stats, 0, 262144, stream);
    fill_f32<<<(4 * P + 255) / 256, 256, 0, stream>>>(out2, -1.0f, 4 * P);

    // ---- unique-rank pipeline ----
    key_kernel<<<nb, 256, 0, stream>>>(pts, d_key, d_cnt, P);
    scanA<<<256, 256, 0, stream>>>(d_cnt, d_off, d_bsum);
    scanB<<<1, 256, 0, stream>>>(d_bsum);
    scanC<<<256, 256, 0, stream>>>(d_off, d_bsum);
    scatter_kernel<<<nb, 256, 0, stream>>>(d_key, d_off, d_fill, d_lo, P);
    bucket_unique<<<NB / 256, 256, 0, stream>>>(d_off, d_cnt, d_lo, d_dcnt, NB);
    scanA<<<256, 256, 0, stream>>>(d_dcnt, d_dpre, d_bsum);
    scanB<<<1, 256, 0, stream>>>(d_bsum);
    scanC<<<256, 256, 0, stream>>>(d_dpre, d_bsum);
    rank_kernel<<<nb, 256, 0, stream>>>(d_key, d_off, d_dcnt, d_lo, d_dpre, d_inv, P);

    // ---- voxel pooling ----
    accum_kernel<<<nb, 256, 0, stream>>>(pts, d_inv, d_counts, d_csum, d_winner, P);
    centroid_kernel<<<nb, 256, 0, stream>>>(d_csum, d_counts, P);
    uvox_kernel<<<nb, 256, 0, stream>>>(pts, d_inv, d_winner, out2, P, N);
    norm_kernel<<<nb, 256, 0, stream>>>(pts, d_inv, d_csum, out3, P);

    // ---- weights -> bf16 W^T ----
    prep_wt<<<208, 256, 0, stream>>>(w2, w3, w4, d_wt2, d_wt3, d_wt4);

    // ---- layer 1: stats only ----
    l1stats<<<P / 64, 128, 0, stream>>>(out3, w1, d_stats, P);
    finalize_bn<<<1, 128, 0, stream>>>(d_stats, g1, b1, d_params, P);

    // ---- layer 2 (recompute norm@w1 in staging) -> pos_raw (bufA) ----
    gemm_layer<128, 1><<<P / 128, 256, 0, stream>>>(
        nullptr, out3, w1, d_params, nullptr, nullptr, d_wt2, d_bufA, d_stats + 1 * 64 * 256, P);
    finalize_bn<<<1, 128, 0, stream>>>(d_stats + 1 * 64 * 256, g2, b2, d_params + 256, P);

    // ---- layer 3 (concat) -> af_raw (bufB) ----
    gemm_layer<160, 2><<<P / 128, 256, 0, stream>>>(
        d_bufA, nullptr, nullptr, d_params + 256, pts, d_csum, d_wt3, d_bufB, d_stats + 2 * 64 * 256, P);
    finalize_bn<<<1, 128, 0, stream>>>(d_stats + 2 * 64 * 256, g3, b3, d_params + 512, P);

    // ---- layer 4 -> agg_raw (bufA) ----
    gemm_layer<128, 0><<<P / 128, 256, 0, stream>>>(
        d_bufB, nullptr, nullptr, d_params + 512, nullptr, nullptr, d_wt4, d_bufA, d_stats + 3 * 64 * 256, P);
    finalize_bn<<<1, 128, 0, stream>>>(d_stats + 3 * 64 * 256, g4, b4, d_params + 768, P);

    // ---- final BN+GELU -> f32 out ----
    bn_gelu_out<<<(P * 128 / 4 + 255) / 256, 256, 0, stream>>>(
        d_bufA, d_params + 768, out0, P * 128);
}

// Round 9
// 626.186 us; speedup vs baseline: 1.5969x; 1.0824x over previous
//
#include <hip/hip_runtime.h>
#include <cstddef>

#define EPSBN 1e-5f

typedef __attribute__((ext_vector_type(8))) short bf16x8;
typedef __attribute__((ext_vector_type(4))) float f32x4;

__device__ __forceinline__ float gelu_f(float x) {
    return 0.5f * x * (1.0f + erff(x * 0.70710678118654752440f));
}

__device__ __forceinline__ float bfu2f(unsigned short u) {
    unsigned v = ((unsigned)u) << 16;
    return __uint_as_float(v);
}

__device__ __forceinline__ unsigned short f2bfu(float f) {
    unsigned u = __float_as_uint(f);
    unsigned r = (u + 0x7fffu + ((u >> 16) & 1u)) >> 16;  // RNE
    return (unsigned short)r;
}

// XOR swizzle valid only where it is a bijection of the row: first 256 bytes.
__device__ __forceinline__ int swz_byte(int byte, int r) {
    return (byte < 256) ? (byte ^ ((r & 7) << 4)) : byte;
}

__device__ __forceinline__ void voxel_idx(const float* __restrict__ pts, int i,
                                          int& vx, int& vy, int& vz) {
    float x = pts[i * 3 + 0], y = pts[i * 3 + 1], z = pts[i * 3 + 2];
    vx = (int)floorf(x / 0.1f);
    vy = (int)floorf(y / 0.1f);
    vz = (int)floorf(z / 0.1f);
}

__device__ __forceinline__ unsigned flip_hash(const float* __restrict__ pts, int i) {
    int vx, vy, vz;
    voxel_idx(pts, i, vx, vy, vz);
    unsigned h = (unsigned)vx * 73856093u + (unsigned)vy * 19349663u + (unsigned)vz * 83492791u;
    return h ^ 0x80000000u;  // unsigned order == signed int32 order
}

__global__ void fill_f32(float* p, float v, int n) {
    int i = blockIdx.x * blockDim.x + threadIdx.x;
    if (i < n) p[i] = v;
}

__global__ void key_kernel(const float* __restrict__ pts, int* __restrict__ key,
                           int* __restrict__ cnt, int P) {
    int i = blockIdx.x * blockDim.x + threadIdx.x;
    if (i >= P) return;
    unsigned fk = flip_hash(pts, i);
    key[i] = (int)fk;
    atomicAdd(&cnt[fk >> 16], 1);
}

// ---- hierarchical exclusive scan of 65536 ints ----
__global__ void scanA(const int* __restrict__ in, int* __restrict__ out, int* __restrict__ bsum) {
    __shared__ int s[256];
    int tid = threadIdx.x;
    int i = blockIdx.x * 256 + tid;
    int v = in[i];
    s[tid] = v;
    __syncthreads();
    for (int off = 1; off < 256; off <<= 1) {
        int t = (tid >= off) ? s[tid - off] : 0;
        __syncthreads();
        s[tid] += t;
        __syncthreads();
    }
    out[i] = s[tid] - v;  // exclusive
    if (tid == 255) bsum[blockIdx.x] = s[255];
}

__global__ void scanB(int* bsum) {
    __shared__ int s[256];
    int tid = threadIdx.x;
    int v = bsum[tid];
    s[tid] = v;
    __syncthreads();
    for (int off = 1; off < 256; off <<= 1) {
        int t = (tid >= off) ? s[tid - off] : 0;
        __syncthreads();
        s[tid] += t;
        __syncthreads();
    }
    bsum[tid] = s[tid] - v;  // exclusive
}

__global__ void scanC(int* __restrict__ out, const int* __restrict__ bsum) {
    out[blockIdx.x * 256 + threadIdx.x] += bsum[blockIdx.x];
}

__global__ void scatter_kernel(const int* __restrict__ key, const int* __restrict__ off,
                               int* __restrict__ fill, int* __restrict__ lo, int P) {
    int i = blockIdx.x * blockDim.x + threadIdx.x;
    if (i >= P) return;
    unsigned fk = (unsigned)key[i];
    int hi = fk >> 16;
    int pos = off[hi] + atomicAdd(&fill[hi], 1);
    lo[pos] = (int)(fk & 0xFFFFu);
}

// per-bucket in-place selection sort + dedupe (no scratch arrays; mean n~4)
__global__ void bucket_unique(const int* __restrict__ off, const int* __restrict__ cnt,
                              int* __restrict__ lo, int* __restrict__ dcnt, int NB) {
    int b = blockIdx.x * blockDim.x + threadIdx.x;
    if (b >= NB) return;
    int n = cnt[b];
    int base = off[b];
    if (n == 0) { dcnt[b] = 0; return; }
    for (int j = 0; j < n - 1; ++j) {
        int mi = j, mv = lo[base + j];
        for (int k = j + 1; k < n; ++k) {
            int v = lo[base + k];
            if (v < mv) { mv = v; mi = k; }
        }
        if (mi != j) { lo[base + mi] = lo[base + j]; lo[base + j] = mv; }
    }
    int d = 0, prev = -1;
    for (int j = 0; j < n; ++j) {
        int v = lo[base + j];
        if (j == 0 || v != prev) lo[base + d++] = v;
        prev = v;
    }
    dcnt[b] = d;
}

__global__ void rank_kernel(const int* __restrict__ key, const int* __restrict__ off,
                            const int* __restrict__ dcnt, const int* __restrict__ lo,
                            const int* __restrict__ dpre, int* __restrict__ inv, int P) {
    int i = blockIdx.x * blockDim.x + threadIdx.x;
    if (i >= P) return;
    unsigned fk = (unsigned)key[i];
    int hi = fk >> 16;
    int l = (int)(fk & 0xFFFFu);
    int base = off[hi];
    int d = dcnt[hi];
    int r = 0;
    for (int j = 0; j < d; ++j) {
        if (lo[base + j] == l) { r = j; break; }
    }
    inv[i] = dpre[hi] + r;
}

__global__ void accum_kernel(const float* __restrict__ pts, const int* __restrict__ inv,
                             float* __restrict__ counts, float* __restrict__ csum,
                             int* __restrict__ winner, int P) {
    int i = blockIdx.x * blockDim.x + threadIdx.x;
    if (i >= P) return;
    int s = inv[i];
    atomicAdd(&counts[s], 1.0f);
    atomicAdd(&csum[s * 3 + 0], pts[i * 3 + 0]);
    atomicAdd(&csum[s * 3 + 1], pts[i * 3 + 1]);
    atomicAdd(&csum[s * 3 + 2], pts[i * 3 + 2]);
    atomicMax(&winner[s], i);  // last point wins (XLA scatter order)
}

__global__ void centroid_kernel(float* __restrict__ csum, const float* __restrict__ counts, int P) {
    int s = blockIdx.x * blockDim.x + threadIdx.x;
    if (s >= P) return;
    float d = fmaxf(counts[s], 1.0f);
    csum[s * 3 + 0] /= d;
    csum[s * 3 + 1] /= d;
    csum[s * 3 + 2] /= d;
}

// fused: norm_points write + uvox winner write (one pass over points)
__global__ void uvox_norm_kernel(const float* __restrict__ pts, const int* __restrict__ inv,
                                 const int* __restrict__ winner, const float* __restrict__ cent,
                                 float* __restrict__ out2, float* __restrict__ out3,
                                 int P, int N) {
    int i = blockIdx.x * blockDim.x + threadIdx.x;
    if (i >= P) return;
    int s = inv[i];
    float px = pts[i * 3 + 0], py = pts[i * 3 + 1], pz = pts[i * 3 + 2];
    out3[i * 3 + 0] = px - cent[s * 3 + 0];
    out3[i * 3 + 1] = py - cent[s * 3 + 1];
    out3[i * 3 + 2] = pz - cent[s * 3 + 2];
    if (winner[s] == i) {
        out2[0 * (size_t)P + s] = (float)(i / N);
        out2[1 * (size_t)P + s] = (float)(int)floorf(px / 0.1f);
        out2[2 * (size_t)P + s] = (float)(int)floorf(py / 0.1f);
        out2[3 * (size_t)P + s] = (float)(int)floorf(pz / 0.1f);
    }
}

// layer-1 stats only (raw1 recomputed in layer-2 staging). 128 threads = cols, 64 rows/block.
__global__ void l1stats(const float* __restrict__ norm, const float* __restrict__ w1g,
                        float* __restrict__ spart, int P) {
    int c = threadIdx.x;
    int row0 = blockIdx.x * 64;
    float w0 = w1g[c], wa = w1g[128 + c], wb = w1g[256 + c];
    float s = 0.f, q = 0.f;
    for (int r = 0; r < 64; ++r) {
        const float* nr = norm + (size_t)(row0 + r) * 3;
        float v = nr[0] * w0 + nr[1] * wa + nr[2] * wb;
        s += v;
        q += v * v;
    }
    int b = blockIdx.x & 63;
    atomicAdd(&spart[b * 256 + c], s);
    atomicAdd(&spart[b * 256 + 128 + c], q);
}

__global__ void finalize_bn(const float* __restrict__ spart, const float* __restrict__ g,
                            const float* __restrict__ b, float* __restrict__ prm, int P) {
    int c = threadIdx.x;  // 128
    float s = 0.f, q = 0.f;
    for (int t = 0; t < 64; ++t) {
        s += spart[t * 256 + c];
        q += spart[t * 256 + 128 + c];
    }
    float m = s / (float)P;
    float var = fmaxf(q / (float)P - m * m, 0.f);
    float A = g[c] * rsqrtf(var + EPSBN);
    prm[c] = A;
    prm[128 + c] = b[c] - A * m;
}

// pre-transpose weights to bf16 W^T[n][k]; layer-3 K reordered [act(128), pts(3), cent(3), 0-pad]
__global__ void prep_wt(const float* __restrict__ w2, const float* __restrict__ w3,
                        const float* __restrict__ w4, unsigned short* __restrict__ wt2,
                        unsigned short* __restrict__ wt3, unsigned short* __restrict__ wt4) {
    int t = blockIdx.x * 256 + threadIdx.x;  // 53248 tasks
    if (t < 16384) {
        int n = t >> 7, k = t & 127;
        wt2[n * 128 + k] = f2bfu(w2[k * 128 + n]);
    } else if (t < 16384 + 20480) {
        int u = t - 16384;
        int n = u / 160, k = u - n * 160;
        float v = 0.f;
        if (k < 134) {
            int r = (k < 128) ? (k + 3) : ((k < 131) ? (k - 128) : k);
            v = w3[r * 128 + n];
        }
        wt3[n * 160 + k] = f2bfu(v);
    } else if (t < 53248) {
        int u = t - 36864;
        int n = u >> 7, k = u & 127;
        wt4[n * 128 + k] = f2bfu(w4[k * 128 + n]);
    }
}

// MFMA GEMM layer, 256 threads (4 waves, 2x2 wave grid), 128x128 tile.
// A staged in LDS (32-40KB); B fragments read DIRECTLY from global W^T (L1/L2-hot,
// 32-40KB) -- no sW, halving LDS so 4 blocks/CU can reside (was 2).
// MODE 0: A = BNGELU(act_raw bf16; prm)
// MODE 1: A = BNGELU(norm @ w1; prm)
// MODE 2: A = [BNGELU(act_raw), pts, cent, 0-pad]  (KPAD=160)
template <int KPAD, int MODE>
__launch_bounds__(256, 2)
__global__ void gemm_layer(const unsigned short* __restrict__ act_raw,
                           const float* __restrict__ norm,
                           const float* __restrict__ w1g,
                           const float* __restrict__ prm,
                           const float* __restrict__ pts,
                           const float* __restrict__ cent,
                           const unsigned short* __restrict__ wt,
                           unsigned short* __restrict__ out_raw,
                           float* __restrict__ spart, int P) {
    __shared__ __align__(16) unsigned short sA[128 * KPAD];
    const int tid = threadIdx.x;
    const int row0 = blockIdx.x * 128;

    // ---- stage A cols 0..127 (4 bf16 = 8B per thread-iter) ----
    for (int e = tid * 4; e < 128 * 128; e += 1024) {
        int r = e >> 7, k = e & 127;
        float v0, v1, v2, v3;
        if constexpr (MODE == 1) {
            const float* nr = norm + (size_t)(row0 + r) * 3;
            float n0 = nr[0], n1 = nr[1], n2 = nr[2];
            float r0 = n0 * w1g[k + 0] + n1 * w1g[128 + k + 0] + n2 * w1g[256 + k + 0];
            float r1 = n0 * w1g[k + 1] + n1 * w1g[128 + k + 1] + n2 * w1g[256 + k + 1];
            float r2 = n0 * w1g[k + 2] + n1 * w1g[128 + k + 2] + n2 * w1g[256 + k + 2];
            float r3 = n0 * w1g[k + 3] + n1 * w1g[128 + k + 3] + n2 * w1g[256 + k + 3];
            float4 pA = *(const float4*)&prm[k];
            float4 pB = *(const float4*)&prm[128 + k];
            v0 = gelu_f(pA.x * r0 + pB.x);
            v1 = gelu_f(pA.y * r1 + pB.y);
            v2 = gelu_f(pA.z * r2 + pB.z);
            v3 = gelu_f(pA.w * r3 + pB.w);
        } else {
            ushort4 rv = *(const ushort4*)&act_raw[(size_t)(row0 + r) * 128 + k];
            float4 pA = *(const float4*)&prm[k];
            float4 pB = *(const float4*)&prm[128 + k];
            v0 = gelu_f(pA.x * bfu2f(rv.x) + pB.x);
            v1 = gelu_f(pA.y * bfu2f(rv.y) + pB.y);
            v2 = gelu_f(pA.z * bfu2f(rv.z) + pB.z);
            v3 = gelu_f(pA.w * bfu2f(rv.w) + pB.w);
        }
        unsigned lo = (unsigned)f2bfu(v0) | ((unsigned)f2bfu(v1) << 16);
        unsigned hi = (unsigned)f2bfu(v2) | ((unsigned)f2bfu(v3) << 16);
        *(uint2*)((char*)sA + r * (KPAD * 2) + swz_byte(k * 2, r)) = make_uint2(lo, hi);
    }
    if constexpr (MODE == 2) {
        // cols 128..159: pts, cent, zeros
        const int NCH = (KPAD - 128) / 4;
        for (int t = tid; t < 128 * NCH; t += 256) {
            int r = t / NCH, ch = t - r * NCH;
            float a = 0.f, b = 0.f, c = 0.f, d = 0.f;
            if (ch == 0) {
                a = pts[(size_t)(row0 + r) * 3 + 0];
                b = pts[(size_t)(row0 + r) * 3 + 1];
                c = pts[(size_t)(row0 + r) * 3 + 2];
                d = cent[(size_t)(row0 + r) * 3 + 0];
            } else if (ch == 1) {
                a = cent[(size_t)(row0 + r) * 3 + 1];
                b = cent[(size_t)(row0 + r) * 3 + 2];
            }
            unsigned lo = (unsigned)f2bfu(a) | ((unsigned)f2bfu(b) << 16);
            unsigned hi = (unsigned)f2bfu(c) | ((unsigned)f2bfu(d) << 16);
            int byte = swz_byte((128 + ch * 4) * 2, r);
            *(uint2*)((char*)sA + r * (KPAD * 2) + byte) = make_uint2(lo, hi);
        }
    }
    __syncthreads();

    const int lane = tid & 63;
    const int wid = tid >> 6;
    const int wm = wid >> 1, wn = wid & 1;  // 2x2 wave grid, 64x64 each
    const int lrow = lane & 15;
    const int kg = lane >> 4;

    // B fragment base: row n = wn*64 + j*16 + lrow of W^T[n][k], k-slice kg*8 + ks*32
    const unsigned short* wbase = wt + (size_t)(wn * 64 + lrow) * KPAD + kg * 8;

    f32x4 acc[4][4] = {};
#pragma unroll
    for (int ks = 0; ks < KPAD / 32; ++ks) {
        bf16x8 a[4], b[4];
        int kbyte = ks * 64 + kg * 16;
#pragma unroll
        for (int j = 0; j < 4; ++j)
            b[j] = *(const bf16x8*)(wbase + (size_t)j * 16 * KPAD + ks * 32);
#pragma unroll
        for (int i = 0; i < 4; ++i) {
            int r = wm * 64 + i * 16 + lrow;
            a[i] = *(const bf16x8*)((const char*)sA + r * (KPAD * 2) + swz_byte(kbyte, r));
        }
#pragma unroll
        for (int i = 0; i < 4; ++i)
#pragma unroll
            for (int j = 0; j < 4; ++j)
                acc[i][j] = __builtin_amdgcn_mfma_f32_16x16x32_bf16(a[i], b[j], acc[i][j], 0, 0, 0);
    }

    // ---- C write (bf16) + column stats ----
    float s[4] = {0.f, 0.f, 0.f, 0.f}, q[4] = {0.f, 0.f, 0.f, 0.f};
#pragma unroll
    for (int i = 0; i < 4; ++i) {
        int rbase = row0 + wm * 64 + i * 16 + kg * 4;
#pragma unroll
        for (int j = 0; j < 4; ++j) {
            int col = wn * 64 + j * 16 + lrow;
#pragma unroll
            for (int reg = 0; reg < 4; ++reg) {
                float v = acc[i][j][reg];
                out_raw[(size_t)(rbase + reg) * 128 + col] = f2bfu(v);
                s[j] += v;
                q[j] += v * v;
            }
        }
    }

    __syncthreads();  // all MFMA LDS reads done; reuse sA as reduction buffer
    float* red = (float*)sA;
    red[tid] = 0.f;
    __syncthreads();
#pragma unroll
    for (int j = 0; j < 4; ++j) {
        int col = wn * 64 + j * 16 + lrow;
        atomicAdd(&red[col], s[j]);
        atomicAdd(&red[128 + col], q[j]);
    }
    __syncthreads();
    atomicAdd(&spart[(blockIdx.x & 63) * 256 + tid], red[tid]);
}

__global__ void bn_gelu_out(const unsigned short* __restrict__ raw, const float* __restrict__ prm,
                            float* __restrict__ out, int n) {
    int i = blockIdx.x * blockDim.x + threadIdx.x;
    int idx4 = i * 4;
    if (idx4 >= n) return;
    ushort4 v = *(const ushort4*)&raw[idx4];
    int c = idx4 & 127;
    float4 o;
    o.x = gelu_f(prm[c + 0] * bfu2f(v.x) + prm[128 + c + 0]);
    o.y = gelu_f(prm[c + 1] * bfu2f(v.y) + prm[128 + c + 1]);
    o.z = gelu_f(prm[c + 2] * bfu2f(v.z) + prm[128 + c + 2]);
    o.w = gelu_f(prm[c + 3] * bfu2f(v.w) + prm[128 + c + 3]);
    *(float4*)&out[idx4] = o;
}

extern "C" void kernel_launch(void* const* d_in, const int* in_sizes, int n_in,
                              void* d_out, int out_size, void* d_ws, size_t ws_size,
                              hipStream_t stream) {
    const float* pts = (const float*)d_in[0];
    const float* w1 = (const float*)d_in[1];
    const float* g1 = (const float*)d_in[2];
    const float* b1 = (const float*)d_in[3];
    const float* w2 = (const float*)d_in[4];
    const float* g2 = (const float*)d_in[5];
    const float* b2 = (const float*)d_in[6];
    const float* w3 = (const float*)d_in[7];
    const float* g3 = (const float*)d_in[8];
    const float* b3 = (const float*)d_in[9];
    const float* w4 = (const float*)d_in[10];
    const float* g4 = (const float*)d_in[11];
    const float* b4 = (const float*)d_in[12];

    const int P = in_sizes[0] / 3;  // 262144
    const int N = P / 4;            // B=4
    const int NB = 65536;

    float* out0 = (float*)d_out;               // aggregated (P,128)
    float* out2 = out0 + (size_t)P * 128;      // uvox.T (4,P)
    float* out3 = out2 + (size_t)P * 4;        // norm_points (P,3)

    char* ws = (char*)d_ws;
    size_t P4 = (size_t)P * 4;
    int* d_key = (int*)(ws + 0 * P4);
    int* d_lo = (int*)(ws + 1 * P4);
    int* d_inv = (int*)(ws + 2 * P4);
    float* d_counts = (float*)(ws + 3 * P4);
    float* d_csum = (float*)(ws + 4 * P4);   // 3P floats; becomes centroids
    int* d_winner = (int*)(ws + 7 * P4);
    char* base8 = ws + 8 * P4;
    int* d_cnt = (int*)(base8);
    int* d_off = (int*)(base8 + 1 * 262144);
    int* d_fill = (int*)(base8 + 2 * 262144);
    int* d_dcnt = (int*)(base8 + 3 * 262144);
    int* d_dpre = (int*)(base8 + 4 * 262144);
    float* d_stats = (float*)(base8 + 5 * 262144);            // 4*64*256 f32 = 256KB
    float* d_params = (float*)(base8 + 6 * 262144);           // 4*256 f32
    int* d_bsum = (int*)(base8 + 6 * 262144 + 16384);         // 256 ints
    unsigned short* d_wt2 = (unsigned short*)(base8 + 6 * 262144 + 65536);
    unsigned short* d_wt3 = d_wt2 + 128 * 128;
    unsigned short* d_wt4 = d_wt3 + 128 * 160;
    char* bufbase = base8 + 6 * 262144 + 65536 + 262144;
    unsigned short* d_bufA = (unsigned short*)bufbase;                         // (P,128) bf16
    unsigned short* d_bufB = (unsigned short*)(bufbase + (size_t)P * 128 * 2); // (P,128) bf16

    const int nb = (P + 255) / 256;

    (void)hipMemsetAsync(d_cnt, 0, 262144, stream);
    (void)hipMemsetAsync(d_fill, 0, 262144, stream);
    (void)hipMemsetAsync(d_counts, 0, P4, stream);
    (void)hipMemsetAsync(d_csum, 0, 3 * P4, stream);
    (void)hipMemsetAsync(d_winner, 0xFF, P4, stream);
    (void)hipMemsetAsync(d_stats, 0, 262144, stream);
    fill_f32<<<(4 * P + 255) / 256, 256, 0, stream>>>(out2, -1.0f, 4 * P);

    // ---- unique-rank pipeline ----
    key_kernel<<<nb, 256, 0, stream>>>(pts, d_key, d_cnt, P);
    scanA<<<256, 256, 0, stream>>>(d_cnt, d_off, d_bsum);
    scanB<<<1, 256, 0, stream>>>(d_bsum);
    scanC<<<256, 256, 0, stream>>>(d_off, d_bsum);
    scatter_kernel<<<nb, 256, 0, stream>>>(d_key, d_off, d_fill, d_lo, P);
    bucket_unique<<<NB / 256, 256, 0, stream>>>(d_off, d_cnt, d_lo, d_dcnt, NB);
    scanA<<<256, 256, 0, stream>>>(d_dcnt, d_dpre, d_bsum);
    scanB<<<1, 256, 0, stream>>>(d_bsum);
    scanC<<<256, 256, 0, stream>>>(d_dpre, d_bsum);
    rank_kernel<<<nb, 256, 0, stream>>>(d_key, d_off, d_dcnt, d_lo, d_dpre, d_inv, P);

    // ---- voxel pooling ----
    accum_kernel<<<nb, 256, 0, stream>>>(pts, d_inv, d_counts, d_csum, d_winner, P);
    centroid_kernel<<<nb, 256, 0, stream>>>(d_csum, d_counts, P);
    uvox_norm_kernel<<<nb, 256, 0, stream>>>(pts, d_inv, d_winner, d_csum, out2, out3, P, N);

    // ---- weights -> bf16 W^T ----
    prep_wt<<<208, 256, 0, stream>>>(w2, w3, w4, d_wt2, d_wt3, d_wt4);

    // ---- layer 1: stats only ----
    l1stats<<<P / 64, 128, 0, stream>>>(out3, w1, d_stats, P);
    finalize_bn<<<1, 128, 0, stream>>>(d_stats, g1, b1, d_params, P);

    // ---- layer 2 (recompute norm@w1 in staging) -> pos_raw (bufA) ----
    gemm_layer<128, 1><<<P / 128, 256, 0, stream>>>(
        nullptr, out3, w1, d_params, nullptr, nullptr, d_wt2, d_bufA, d_stats + 1 * 64 * 256, P);
    finalize_bn<<<1, 128, 0, stream>>>(d_stats + 1 * 64 * 256, g2, b2, d_params + 256, P);

    // ---- layer 3 (concat) -> af_raw (bufB) ----
    gemm_layer<160, 2><<<P / 128, 256, 0, stream>>>(
        d_bufA, nullptr, nullptr, d_params + 256, pts, d_csum, d_wt3, d_bufB, d_stats + 2 * 64 * 256, P);
    finalize_bn<<<1, 128, 0, stream>>>(d_stats + 2 * 64 * 256, g3, b3, d_params + 512, P);

    // ---- layer 4 -> agg_raw (bufA) ----
    gemm_layer<128, 0><<<P / 128, 256, 0, stream>>>(
        d_bufB, nullptr, nullptr, d_params + 512, nullptr, nullptr, d_wt4, d_bufA, d_stats + 3 * 64 * 256, P);
    finalize_bn<<<1, 128, 0, stream>>>(d_stats + 3 * 64 * 256, g4, b4, d_params + 768, P);

    // ---- final BN+GELU -> f32 out ----
    bn_gelu_out<<<(P * 128 / 4 + 255) / 256, 256, 0, stream>>>(
        d_bufA, d_params + 768, out0, P * 128);
}

// Round 10
// 581.771 us; speedup vs baseline: 1.7188x; 1.0763x over previous
//
#include <hip/hip_runtime.h>
#include <cstddef>

#define EPSBN 1e-5f

typedef __attribute__((ext_vector_type(8))) short bf16x8;
typedef __attribute__((ext_vector_type(4))) float f32x4;

__device__ __forceinline__ float gelu_f(float x) {
    return 0.5f * x * (1.0f + erff(x * 0.70710678118654752440f));
}

__device__ __forceinline__ float bfu2f(unsigned short u) {
    unsigned v = ((unsigned)u) << 16;
    return __uint_as_float(v);
}

__device__ __forceinline__ unsigned short f2bfu(float f) {
    unsigned u = __float_as_uint(f);
    unsigned r = (u + 0x7fffu + ((u >> 16) & 1u)) >> 16;  // RNE
    return (unsigned short)r;
}

// XOR swizzle valid only where it is a bijection of the row: first 256 bytes.
__device__ __forceinline__ int swz_byte(int byte, int r) {
    return (byte < 256) ? (byte ^ ((r & 7) << 4)) : byte;
}

__device__ __forceinline__ void voxel_idx(const float* __restrict__ pts, int i,
                                          int& vx, int& vy, int& vz) {
    float x = pts[i * 3 + 0], y = pts[i * 3 + 1], z = pts[i * 3 + 2];
    vx = (int)floorf(x / 0.1f);
    vy = (int)floorf(y / 0.1f);
    vz = (int)floorf(z / 0.1f);
}

__device__ __forceinline__ unsigned flip_hash(const float* __restrict__ pts, int i) {
    int vx, vy, vz;
    voxel_idx(pts, i, vx, vy, vz);
    unsigned h = (unsigned)vx * 73856093u + (unsigned)vy * 19349663u + (unsigned)vz * 83492791u;
    return h ^ 0x80000000u;  // unsigned order == signed int32 order
}

__global__ void fill_f32(float* p, float v, int n) {
    int i = blockIdx.x * blockDim.x + threadIdx.x;
    if (i < n) p[i] = v;
}

__global__ void key_kernel(const float* __restrict__ pts, int* __restrict__ key,
                           int* __restrict__ cnt, int P) {
    int i = blockIdx.x * blockDim.x + threadIdx.x;
    if (i >= P) return;
    unsigned fk = flip_hash(pts, i);
    key[i] = (int)fk;
    atomicAdd(&cnt[fk >> 16], 1);
}

// ---- hierarchical exclusive scan of 65536 ints ----
__global__ void scanA(const int* __restrict__ in, int* __restrict__ out, int* __restrict__ bsum) {
    __shared__ int s[256];
    int tid = threadIdx.x;
    int i = blockIdx.x * 256 + tid;
    int v = in[i];
    s[tid] = v;
    __syncthreads();
    for (int off = 1; off < 256; off <<= 1) {
        int t = (tid >= off) ? s[tid - off] : 0;
        __syncthreads();
        s[tid] += t;
        __syncthreads();
    }
    out[i] = s[tid] - v;  // exclusive
    if (tid == 255) bsum[blockIdx.x] = s[255];
}

__global__ void scanB(int* bsum) {
    __shared__ int s[256];
    int tid = threadIdx.x;
    int v = bsum[tid];
    s[tid] = v;
    __syncthreads();
    for (int off = 1; off < 256; off <<= 1) {
        int t = (tid >= off) ? s[tid - off] : 0;
        __syncthreads();
        s[tid] += t;
        __syncthreads();
    }
    bsum[tid] = s[tid] - v;  // exclusive
}

__global__ void scanC(int* __restrict__ out, const int* __restrict__ bsum) {
    out[blockIdx.x * 256 + threadIdx.x] += bsum[blockIdx.x];
}

__global__ void scatter_kernel(const int* __restrict__ key, const int* __restrict__ off,
                               int* __restrict__ fill, int* __restrict__ lo, int P) {
    int i = blockIdx.x * blockDim.x + threadIdx.x;
    if (i >= P) return;
    unsigned fk = (unsigned)key[i];
    int hi = fk >> 16;
    int pos = off[hi] + atomicAdd(&fill[hi], 1);
    lo[pos] = (int)(fk & 0xFFFFu);
}

// per-bucket in-place selection sort + dedupe (no scratch arrays; mean n~4)
__global__ void bucket_unique(const int* __restrict__ off, const int* __restrict__ cnt,
                              int* __restrict__ lo, int* __restrict__ dcnt, int NB) {
    int b = blockIdx.x * blockDim.x + threadIdx.x;
    if (b >= NB) return;
    int n = cnt[b];
    int base = off[b];
    if (n == 0) { dcnt[b] = 0; return; }
    for (int j = 0; j < n - 1; ++j) {
        int mi = j, mv = lo[base + j];
        for (int k = j + 1; k < n; ++k) {
            int v = lo[base + k];
            if (v < mv) { mv = v; mi = k; }
        }
        if (mi != j) { lo[base + mi] = lo[base + j]; lo[base + j] = mv; }
    }
    int d = 0, prev = -1;
    for (int j = 0; j < n; ++j) {
        int v = lo[base + j];
        if (j == 0 || v != prev) lo[base + d++] = v;
        prev = v;
    }
    dcnt[b] = d;
}

__global__ void rank_kernel(const int* __restrict__ key, const int* __restrict__ off,
                            const int* __restrict__ dcnt, const int* __restrict__ lo,
                            const int* __restrict__ dpre, int* __restrict__ inv, int P) {
    int i = blockIdx.x * blockDim.x + threadIdx.x;
    if (i >= P) return;
    unsigned fk = (unsigned)key[i];
    int hi = fk >> 16;
    int l = (int)(fk & 0xFFFFu);
    int base = off[hi];
    int d = dcnt[hi];
    int r = 0;
    for (int j = 0; j < d; ++j) {
        if (lo[base + j] == l) { r = j; break; }
    }
    inv[i] = dpre[hi] + r;
}

__global__ void accum_kernel(const float* __restrict__ pts, const int* __restrict__ inv,
                             float* __restrict__ counts, float* __restrict__ csum,
                             int* __restrict__ winner, int P) {
    int i = blockIdx.x * blockDim.x + threadIdx.x;
    if (i >= P) return;
    int s = inv[i];
    atomicAdd(&counts[s], 1.0f);
    atomicAdd(&csum[s * 3 + 0], pts[i * 3 + 0]);
    atomicAdd(&csum[s * 3 + 1], pts[i * 3 + 1]);
    atomicAdd(&csum[s * 3 + 2], pts[i * 3 + 2]);
    atomicMax(&winner[s], i);  // last point wins (XLA scatter order)
}

__global__ void centroid_kernel(float* __restrict__ csum, const float* __restrict__ counts, int P) {
    int s = blockIdx.x * blockDim.x + threadIdx.x;
    if (s >= P) return;
    float d = fmaxf(counts[s], 1.0f);
    csum[s * 3 + 0] /= d;
    csum[s * 3 + 1] /= d;
    csum[s * 3 + 2] /= d;
}

// fused: norm_points write + uvox winner write (one pass over points)
__global__ void uvox_norm_kernel(const float* __restrict__ pts, const int* __restrict__ inv,
                                 const int* __restrict__ winner, const float* __restrict__ cent,
                                 float* __restrict__ out2, float* __restrict__ out3,
                                 int P, int N) {
    int i = blockIdx.x * blockDim.x + threadIdx.x;
    if (i >= P) return;
    int s = inv[i];
    float px = pts[i * 3 + 0], py = pts[i * 3 + 1], pz = pts[i * 3 + 2];
    out3[i * 3 + 0] = px - cent[s * 3 + 0];
    out3[i * 3 + 1] = py - cent[s * 3 + 1];
    out3[i * 3 + 2] = pz - cent[s * 3 + 2];
    if (winner[s] == i) {
        out2[0 * (size_t)P + s] = (float)(i / N);
        out2[1 * (size_t)P + s] = (float)(int)floorf(px / 0.1f);
        out2[2 * (size_t)P + s] = (float)(int)floorf(py / 0.1f);
        out2[3 * (size_t)P + s] = (float)(int)floorf(pz / 0.1f);
    }
}

// layer-1 stats only (raw1 recomputed in layer-2 staging). 128 threads = cols, 64 rows/block.
__global__ void l1stats(const float* __restrict__ norm, const float* __restrict__ w1g,
                        float* __restrict__ spart, int P) {
    int c = threadIdx.x;
    int row0 = blockIdx.x * 64;
    float w0 = w1g[c], wa = w1g[128 + c], wb = w1g[256 + c];
    float s = 0.f, q = 0.f;
    for (int r = 0; r < 64; ++r) {
        const float* nr = norm + (size_t)(row0 + r) * 3;
        float v = nr[0] * w0 + nr[1] * wa + nr[2] * wb;
        s += v;
        q += v * v;
    }
    int b = blockIdx.x & 63;
    atomicAdd(&spart[b * 256 + c], s);
    atomicAdd(&spart[b * 256 + 128 + c], q);
}

__global__ void finalize_bn(const float* __restrict__ spart, const float* __restrict__ g,
                            const float* __restrict__ b, float* __restrict__ prm, int P) {
    int c = threadIdx.x;  // 128
    float s = 0.f, q = 0.f;
    for (int t = 0; t < 64; ++t) {
        s += spart[t * 256 + c];
        q += spart[t * 256 + 128 + c];
    }
    float m = s / (float)P;
    float var = fmaxf(q / (float)P - m * m, 0.f);
    float A = g[c] * rsqrtf(var + EPSBN);
    prm[c] = A;
    prm[128 + c] = b[c] - A * m;
}

// pre-transpose weights to bf16 W^T[n][k]; layer-3 K reordered [act(128), pts(3), cent(3), 0-pad]
__global__ void prep_wt(const float* __restrict__ w2, const float* __restrict__ w3,
                        const float* __restrict__ w4, unsigned short* __restrict__ wt2,
                        unsigned short* __restrict__ wt3, unsigned short* __restrict__ wt4) {
    int t = blockIdx.x * 256 + threadIdx.x;  // 53248 tasks
    if (t < 16384) {
        int n = t >> 7, k = t & 127;
        wt2[n * 128 + k] = f2bfu(w2[k * 128 + n]);
    } else if (t < 16384 + 20480) {
        int u = t - 16384;
        int n = u / 160, k = u - n * 160;
        float v = 0.f;
        if (k < 134) {
            int r = (k < 128) ? (k + 3) : ((k < 131) ? (k - 128) : k);
            v = w3[r * 128 + n];
        }
        wt3[n * 160 + k] = f2bfu(v);
    } else if (t < 53248) {
        int u = t - 36864;
        int n = u >> 7, k = u & 127;
        wt4[n * 128 + k] = f2bfu(w4[k * 128 + n]);
    }
}

// MFMA GEMM layer, 256 threads (4 waves, 1x4 wave grid), 64x128 tile.
// Small LDS (16-20KB) -> many blocks/CU so stage-phase of one block overlaps
// MFMA-phase of others. B fragments direct from global W^T (L1-hot).
// MODE 0: A = BNGELU(act_raw bf16; prm)
// MODE 1: A = BNGELU(norm @ w1; prm)
// MODE 2: A = [BNGELU(act_raw), pts, cent, 0-pad]  (KPAD=160)
template <int KPAD, int MODE>
__launch_bounds__(256, 2)
__global__ void gemm_layer(const unsigned short* __restrict__ act_raw,
                           const float* __restrict__ norm,
                           const float* __restrict__ w1g,
                           const float* __restrict__ prm,
                           const float* __restrict__ pts,
                           const float* __restrict__ cent,
                           const unsigned short* __restrict__ wt,
                           unsigned short* __restrict__ out_raw,
                           float* __restrict__ spart, int P) {
    __shared__ __align__(16) unsigned short sA[64 * KPAD];
    const int tid = threadIdx.x;
    const int row0 = blockIdx.x * 64;

    // ---- stage A cols 0..127 (4 bf16 = 8B per thread-iter, 8 iters) ----
    for (int e = tid * 4; e < 64 * 128; e += 1024) {
        int r = e >> 7, k = e & 127;
        float v0, v1, v2, v3;
        if constexpr (MODE == 1) {
            const float* nr = norm + (size_t)(row0 + r) * 3;
            float n0 = nr[0], n1 = nr[1], n2 = nr[2];
            float r0 = n0 * w1g[k + 0] + n1 * w1g[128 + k + 0] + n2 * w1g[256 + k + 0];
            float r1 = n0 * w1g[k + 1] + n1 * w1g[128 + k + 1] + n2 * w1g[256 + k + 1];
            float r2 = n0 * w1g[k + 2] + n1 * w1g[128 + k + 2] + n2 * w1g[256 + k + 2];
            float r3 = n0 * w1g[k + 3] + n1 * w1g[128 + k + 3] + n2 * w1g[256 + k + 3];
            float4 pA = *(const float4*)&prm[k];
            float4 pB = *(const float4*)&prm[128 + k];
            v0 = gelu_f(pA.x * r0 + pB.x);
            v1 = gelu_f(pA.y * r1 + pB.y);
            v2 = gelu_f(pA.z * r2 + pB.z);
            v3 = gelu_f(pA.w * r3 + pB.w);
        } else {
            ushort4 rv = *(const ushort4*)&act_raw[(size_t)(row0 + r) * 128 + k];
            float4 pA = *(const float4*)&prm[k];
            float4 pB = *(const float4*)&prm[128 + k];
            v0 = gelu_f(pA.x * bfu2f(rv.x) + pB.x);
            v1 = gelu_f(pA.y * bfu2f(rv.y) + pB.y);
            v2 = gelu_f(pA.z * bfu2f(rv.z) + pB.z);
            v3 = gelu_f(pA.w * bfu2f(rv.w) + pB.w);
        }
        unsigned lo = (unsigned)f2bfu(v0) | ((unsigned)f2bfu(v1) << 16);
        unsigned hi = (unsigned)f2bfu(v2) | ((unsigned)f2bfu(v3) << 16);
        *(uint2*)((char*)sA + r * (KPAD * 2) + swz_byte(k * 2, r)) = make_uint2(lo, hi);
    }
    if constexpr (MODE == 2) {
        // cols 128..159: pts, cent, zeros
        for (int t = tid; t < 64 * 8; t += 256) {
            int r = t >> 3, ch = t & 7;
            float a = 0.f, b = 0.f, c = 0.f, d = 0.f;
            if (ch == 0) {
                a = pts[(size_t)(row0 + r) * 3 + 0];
                b = pts[(size_t)(row0 + r) * 3 + 1];
                c = pts[(size_t)(row0 + r) * 3 + 2];
                d = cent[(size_t)(row0 + r) * 3 + 0];
            } else if (ch == 1) {
                a = cent[(size_t)(row0 + r) * 3 + 1];
                b = cent[(size_t)(row0 + r) * 3 + 2];
            }
            unsigned lo = (unsigned)f2bfu(a) | ((unsigned)f2bfu(b) << 16);
            unsigned hi = (unsigned)f2bfu(c) | ((unsigned)f2bfu(d) << 16);
            int byte = swz_byte((128 + ch * 4) * 2, r);
            *(uint2*)((char*)sA + r * (KPAD * 2) + byte) = make_uint2(lo, hi);
        }
    }
    __syncthreads();

    const int lane = tid & 63;
    const int wid = tid >> 6;   // 0..3 -> column quarter
    const int lrow = lane & 15;
    const int kg = lane >> 4;

    // B fragment base: row n = wid*32 + j*16 + lrow of W^T[n][k], k-slice kg*8 + ks*32
    const unsigned short* wbase = wt + (size_t)(wid * 32 + lrow) * KPAD + kg * 8;

    f32x4 acc[4][2] = {};
#pragma unroll
    for (int ks = 0; ks < KPAD / 32; ++ks) {
        bf16x8 a[4], b[2];
        int kbyte = ks * 64 + kg * 16;
#pragma unroll
        for (int j = 0; j < 2; ++j)
            b[j] = *(const bf16x8*)(wbase + (size_t)j * 16 * KPAD + ks * 32);
#pragma unroll
        for (int i = 0; i < 4; ++i) {
            int r = i * 16 + lrow;
            a[i] = *(const bf16x8*)((const char*)sA + r * (KPAD * 2) + swz_byte(kbyte, r));
        }
#pragma unroll
        for (int i = 0; i < 4; ++i)
#pragma unroll
            for (int j = 0; j < 2; ++j)
                acc[i][j] = __builtin_amdgcn_mfma_f32_16x16x32_bf16(a[i], b[j], acc[i][j], 0, 0, 0);
    }

    // ---- C write (bf16) + column stats ----
    float s[2] = {0.f, 0.f}, q[2] = {0.f, 0.f};
#pragma unroll
    for (int i = 0; i < 4; ++i) {
        int rbase = row0 + i * 16 + kg * 4;
#pragma unroll
        for (int j = 0; j < 2; ++j) {
            int col = wid * 32 + j * 16 + lrow;
#pragma unroll
            for (int reg = 0; reg < 4; ++reg) {
                float v = acc[i][j][reg];
                out_raw[(size_t)(rbase + reg) * 128 + col] = f2bfu(v);
                s[j] += v;
                q[j] += v * v;
            }
        }
    }

    __syncthreads();  // all MFMA LDS reads done; reuse sA as reduction buffer
    float* red = (float*)sA;
    red[tid] = 0.f;
    __syncthreads();
#pragma unroll
    for (int j = 0; j < 2; ++j) {
        int col = wid * 32 + j * 16 + lrow;
        atomicAdd(&red[col], s[j]);
        atomicAdd(&red[128 + col], q[j]);
    }
    __syncthreads();
    atomicAdd(&spart[(blockIdx.x & 63) * 256 + tid], red[tid]);
}

__global__ void bn_gelu_out(const unsigned short* __restrict__ raw, const float* __restrict__ prm,
                            float* __restrict__ out, int n) {
    int i = blockIdx.x * blockDim.x + threadIdx.x;
    int idx4 = i * 4;
    if (idx4 >= n) return;
    ushort4 v = *(const ushort4*)&raw[idx4];
    int c = idx4 & 127;
    float4 o;
    o.x = gelu_f(prm[c + 0] * bfu2f(v.x) + prm[128 + c + 0]);
    o.y = gelu_f(prm[c + 1] * bfu2f(v.y) + prm[128 + c + 1]);
    o.z = gelu_f(prm[c + 2] * bfu2f(v.z) + prm[128 + c + 2]);
    o.w = gelu_f(prm[c + 3] * bfu2f(v.w) + prm[128 + c + 3]);
    *(float4*)&out[idx4] = o;
}

extern "C" void kernel_launch(void* const* d_in, const int* in_sizes, int n_in,
                              void* d_out, int out_size, void* d_ws, size_t ws_size,
                              hipStream_t stream) {
    const float* pts = (const float*)d_in[0];
    const float* w1 = (const float*)d_in[1];
    const float* g1 = (const float*)d_in[2];
    const float* b1 = (const float*)d_in[3];
    const float* w2 = (const float*)d_in[4];
    const float* g2 = (const float*)d_in[5];
    const float* b2 = (const float*)d_in[6];
    const float* w3 = (const float*)d_in[7];
    const float* g3 = (const float*)d_in[8];
    const float* b3 = (const float*)d_in[9];
    const float* w4 = (const float*)d_in[10];
    const float* g4 = (const float*)d_in[11];
    const float* b4 = (const float*)d_in[12];

    const int P = in_sizes[0] / 3;  // 262144
    const int N = P / 4;            // B=4
    const int NB = 65536;

    float* out0 = (float*)d_out;               // aggregated (P,128)
    float* out2 = out0 + (size_t)P * 128;      // uvox.T (4,P)
    float* out3 = out2 + (size_t)P * 4;        // norm_points (P,3)

    char* ws = (char*)d_ws;
    size_t P4 = (size_t)P * 4;
    int* d_key = (int*)(ws + 0 * P4);
    int* d_lo = (int*)(ws + 1 * P4);
    int* d_inv = (int*)(ws + 2 * P4);
    float* d_counts = (float*)(ws + 3 * P4);
    float* d_csum = (float*)(ws + 4 * P4);   // 3P floats; becomes centroids
    int* d_winner = (int*)(ws + 7 * P4);
    char* base8 = ws + 8 * P4;
    int* d_cnt = (int*)(base8);
    int* d_off = (int*)(base8 + 1 * 262144);
    int* d_fill = (int*)(base8 + 2 * 262144);
    int* d_dcnt = (int*)(base8 + 3 * 262144);
    int* d_dpre = (int*)(base8 + 4 * 262144);
    float* d_stats = (float*)(base8 + 5 * 262144);            // 4*64*256 f32 = 256KB
    float* d_params = (float*)(base8 + 6 * 262144);           // 4*256 f32
    int* d_bsum = (int*)(base8 + 6 * 262144 + 16384);         // 256 ints
    unsigned short* d_wt2 = (unsigned short*)(base8 + 6 * 262144 + 65536);
    unsigned short* d_wt3 = d_wt2 + 128 * 128;
    unsigned short* d_wt4 = d_wt3 + 128 * 160;
    char* bufbase = base8 + 6 * 262144 + 65536 + 262144;
    unsigned short* d_bufA = (unsigned short*)bufbase;                         // (P,128) bf16
    unsigned short* d_bufB = (unsigned short*)(bufbase + (size_t)P * 128 * 2); // (P,128) bf16

    const int nb = (P + 255) / 256;

    (void)hipMemsetAsync(d_cnt, 0, 262144, stream);
    (void)hipMemsetAsync(d_fill, 0, 262144, stream);
    (void)hipMemsetAsync(d_counts, 0, P4, stream);
    (void)hipMemsetAsync(d_csum, 0, 3 * P4, stream);
    (void)hipMemsetAsync(d_winner, 0xFF, P4, stream);
    (void)hipMemsetAsync(d_stats, 0, 262144, stream);
    fill_f32<<<(4 * P + 255) / 256, 256, 0, stream>>>(out2, -1.0f, 4 * P);

    // ---- unique-rank pipeline ----
    key_kernel<<<nb, 256, 0, stream>>>(pts, d_key, d_cnt, P);
    scanA<<<256, 256, 0, stream>>>(d_cnt, d_off, d_bsum);
    scanB<<<1, 256, 0, stream>>>(d_bsum);
    scanC<<<256, 256, 0, stream>>>(d_off, d_bsum);
    scatter_kernel<<<nb, 256, 0, stream>>>(d_key, d_off, d_fill, d_lo, P);
    bucket_unique<<<NB / 256, 256, 0, stream>>>(d_off, d_cnt, d_lo, d_dcnt, NB);
    scanA<<<256, 256, 0, stream>>>(d_dcnt, d_dpre, d_bsum);
    scanB<<<1, 256, 0, stream>>>(d_bsum);
    scanC<<<256, 256, 0, stream>>>(d_dpre, d_bsum);
    rank_kernel<<<nb, 256, 0, stream>>>(d_key, d_off, d_dcnt, d_lo, d_dpre, d_inv, P);

    // ---- voxel pooling ----
    accum_kernel<<<nb, 256, 0, stream>>>(pts, d_inv, d_counts, d_csum, d_winner, P);
    centroid_kernel<<<nb, 256, 0, stream>>>(d_csum, d_counts, P);
    uvox_norm_kernel<<<nb, 256, 0, stream>>>(pts, d_inv, d_winner, d_csum, out2, out3, P, N);

    // ---- weights -> bf16 W^T ----
    prep_wt<<<208, 256, 0, stream>>>(w2, w3, w4, d_wt2, d_wt3, d_wt4);

    // ---- layer 1: stats only ----
    l1stats<<<P / 64, 128, 0, stream>>>(out3, w1, d_stats, P);
    finalize_bn<<<1, 128, 0, stream>>>(d_stats, g1, b1, d_params, P);

    // ---- layer 2 (recompute norm@w1 in staging) -> pos_raw (bufA) ----
    gemm_layer<128, 1><<<P / 64, 256, 0, stream>>>(
        nullptr, out3, w1, d_params, nullptr, nullptr, d_wt2, d_bufA, d_stats + 1 * 64 * 256, P);
    finalize_bn<<<1, 128, 0, stream>>>(d_stats + 1 * 64 * 256, g2, b2, d_params + 256, P);

    // ---- layer 3 (concat) -> af_raw (bufB) ----
    gemm_layer<160, 2><<<P / 64, 256, 0, stream>>>(
        d_bufA, nullptr, nullptr, d_params + 256, pts, d_csum, d_wt3, d_bufB, d_stats + 2 * 64 * 256, P);
    finalize_bn<<<1, 128, 0, stream>>>(d_stats + 2 * 64 * 256, g3, b3, d_params + 512, P);

    // ---- layer 4 -> agg_raw (bufA) ----
    gemm_layer<128, 0><<<P / 64, 256, 0, stream>>>(
        d_bufB, nullptr, nullptr, d_params + 512, nullptr, nullptr, d_wt4, d_bufA, d_stats + 3 * 64 * 256, P);
    finalize_bn<<<1, 128, 0, stream>>>(d_stats + 3 * 64 * 256, g4, b4, d_params + 768, P);

    // ---- final BN+GELU -> f32 out ----
    bn_gelu_out<<<(P * 128 / 4 + 255) / 256, 256, 0, stream>>>(
        d_bufA, d_params + 768, out0, P * 128);
}